// Round 1
// baseline (690.992 us; speedup 1.0000x reference)
//
#include <hip/hip_runtime.h>
#include <hip/hip_bf16.h>

#define D 64
#define CAP 32      // slots per node = one 64B line (row == line)
#define OVF_CAP 16384
#define NSHARD 8    // dst shards, bound to XCDs via blockIdx&7 heuristic

// ================= ROUND-19 MEASUREMENT PROBE =================
// Top-5 rocprof rows are all harness ws-poison fills (~45us) => every kernel
// is <= ~44us, but the split of the 157us total is invisible. Inflate each
// kernel with IDEMPOTENT internal reps so each dispatch exceeds 45us and
// lands in the top-5 table with its own duration:
//   M = dur(node_mlp)/MLP_REPS
//   A = dur(append)/APPEND_REPS     (rep0 real, reps 1..7 dry: atomicAdd+0,
//                                    shadow-store to slots2 -> race-free)
//   X = dur(gather)/GATHER_REPS
//   V = 157.1 - M - A - X           (fixed graph/launch overhead)
// Correctness is bit-identical to the r18 kernel; dur_us will regress to
// ~16M+8A+8X+V by design. REVERT REPS TO 1 NEXT ROUND.
#define MLP_REPS 16
#define APPEND_REPS 8
#define GATHER_REPS 8
// ==============================================================

__device__ __forceinline__ float bf2f(unsigned short u) {
    return __uint_as_float((unsigned int)u << 16);
}
__device__ __forceinline__ unsigned short f2bf(float f) {
    unsigned int u = __float_as_uint(f);
    unsigned int r = (u + 0x7fffu + ((u >> 16) & 1u)) >> 16;   // RNE
    return (unsigned short)r;
}

// ---------- Kernel 1: m[n][:] = bf16(relu(x @ W + b)); zero cnt/ovf ----------
__global__ __launch_bounds__(256) void node_mlp_kernel(
    const float* __restrict__ x, const float* __restrict__ W,
    const float* __restrict__ b, unsigned short* __restrict__ m,
    int* __restrict__ cnt, int* __restrict__ ovf_cnt, int n_nodes) {
    const int lane = threadIdx.x & 63;
    float w[D];
    #pragma unroll
    for (int k = 0; k < D; ++k) w[k] = W[k * D + lane];
    const float bias = b[lane];

    const int wave = (blockIdx.x * blockDim.x + threadIdx.x) >> 6;
    const int nwaves = (gridDim.x * blockDim.x) >> 6;

    for (int rep = 0; rep < MLP_REPS; ++rep) {
        asm volatile("" ::: "memory");   // force reloads each rep (no hoist)
        for (int i = blockIdx.x * blockDim.x + threadIdx.x; i < n_nodes;
             i += gridDim.x * blockDim.x) cnt[i] = 0;
        if (blockIdx.x == 0 && threadIdx.x == 0) *ovf_cnt = 0;

        for (int row = wave; row < n_nodes; row += nwaves) {
            const float4* xr = (const float4*)(x + (size_t)row * D);
            float acc = bias;
            #pragma unroll
            for (int kk = 0; kk < D / 4; ++kk) {
                float4 xv = xr[kk];   // wave-uniform address -> broadcast, 1 request
                acc = fmaf(xv.x, w[4 * kk + 0], acc);
                acc = fmaf(xv.y, w[4 * kk + 1], acc);
                acc = fmaf(xv.z, w[4 * kk + 2], acc);
                acc = fmaf(xv.w, w[4 * kk + 3], acc);
            }
            m[(size_t)row * D + lane] = f2bf(fmaxf(acc, 0.0f));   // side effect every rep
        }
    }
}

// ---------- Kernel 2: XCD-sharded append (r12 form) + dry-rep probe ----------
// rep 0 is the REAL append. Dry reps replay the identical memory pattern:
// same dst/src loads, same filter, atomicAdd(&cnt[d],0) (same memory-side RMW,
// value-neutral and order-independent -> safe while other blocks still append),
// and the dependent scattered 2B store targets shadow slots2 (never read).
__global__ __launch_bounds__(256) void append_kernel(
    const int* __restrict__ src, const int* __restrict__ dst,
    int* __restrict__ cnt, unsigned short* __restrict__ slots,
    unsigned short* __restrict__ slots2,
    int* __restrict__ ovf_cnt, unsigned int* __restrict__ ovf,
    int n_edges, int blocks_per_shard) {
    const int shard = blockIdx.x & (NSHARD - 1);
    const int p = blockIdx.x >> 3;          // rank within shard group
    const int chunk = (n_edges + blocks_per_shard - 1) / blocks_per_shard;
    const int beg = p * chunk;
    const int end = min(beg + chunk, n_edges);

    for (int rep = 0; rep < APPEND_REPS; ++rep) {
        asm volatile("" ::: "memory");
        const bool real = (rep == 0);
        for (int e = beg + (int)threadIdx.x; e < end; e += 256) {
            int d = dst[e];                      // coalesced; L3-served (8x redundant)
            if ((d & (NSHARD - 1)) != shard) continue;
            int s = src[e];
            if (real) {
                int pos = atomicAdd(&cnt[d], 1);     // memory-side atomic
                if (pos < CAP) {
                    slots[(size_t)d * CAP + pos] = (unsigned short)s;
                } else {                             // ~4 nodes expected (P(deg>32)~8e-5)
                    int op = atomicAdd(ovf_cnt, 1);
                    if (op < OVF_CAP)
                        ovf[op] = ((unsigned int)d << 16) | (unsigned int)s;
                }
            } else {
                int pos = atomicAdd(&cnt[d], 0);     // identical RMW, value-neutral
                if (pos > CAP - 1) pos = CAP - 1;    // clamp into shadow row
                slots2[(size_t)d * CAP + pos] = (unsigned short)s;  // dependent store
            }
        }
    }
}

// ---------- Kernel 3: gather — one wave/node, fully scalar addressing ----------
__global__ __launch_bounds__(256) void gather_kernel(
    const unsigned short* __restrict__ slots, const int* __restrict__ cnt,
    const unsigned short* __restrict__ m,
    const int* __restrict__ ovf_cnt, const unsigned int* __restrict__ ovf,
    float* __restrict__ out, int n_nodes) {
    const int grp = blockIdx.x >> 3;          // 8-block group covers 32 nodes
    const int xcd = blockIdx.x & 7;
    int node = grp * 32 + ((threadIdx.x >> 6) << 3) + xcd;  // node&7 == blockIdx&7
    if (node >= n_nodes) return;              // wave-uniform branch
    node = __builtin_amdgcn_readfirstlane(node);

    const int lane = threadIdx.x & 63;

    for (int rep = 0; rep < GATHER_REPS; ++rep) {
        asm volatile("" ::: "memory");        // force reloads each rep
        const int c = cnt[node];              // scalar load
        const int cc = min(c, CAP);
        const unsigned int* __restrict__ row =
            (const unsigned int*)(slots + (size_t)node * CAP);  // scalar base

        float acc = 0.0f;
        int k = 0;
        for (; k + 16 <= cc; k += 16) {
            unsigned int p[8];
            #pragma unroll
            for (int i = 0; i < 8; ++i) p[i] = row[(k >> 1) + i];  // s_load x8
            float v[16];
            #pragma unroll
            for (int i = 0; i < 8; ++i) {         // 16 saddr loads in flight
                const unsigned short* ba = m + (size_t)(p[i] & 0xFFFFu) * D; // SGPR base
                const unsigned short* bb = m + (size_t)(p[i] >> 16) * D;     // SGPR base
                v[2 * i + 0] = bf2f(ba[lane]);    // global_load_ushort v, vlane2, s[..]
                v[2 * i + 1] = bf2f(bb[lane]);
            }
            float t0 = ((v[0] + v[1]) + (v[2] + v[3])) + ((v[4] + v[5]) + (v[6] + v[7]));
            float t1 = ((v[8] + v[9]) + (v[10] + v[11])) + ((v[12] + v[13]) + (v[14] + v[15]));
            acc += t0 + t1;
        }
        for (; k + 4 <= cc; k += 4) {
            unsigned int p0 = row[(k >> 1) + 0];
            unsigned int p1 = row[(k >> 1) + 1];
            const unsigned short* b0 = m + (size_t)(p0 & 0xFFFFu) * D;
            const unsigned short* b1 = m + (size_t)(p0 >> 16) * D;
            const unsigned short* b2 = m + (size_t)(p1 & 0xFFFFu) * D;
            const unsigned short* b3 = m + (size_t)(p1 >> 16) * D;
            float v0 = bf2f(b0[lane]);
            float v1 = bf2f(b1[lane]);
            float v2 = bf2f(b2[lane]);
            float v3 = bf2f(b3[lane]);
            acc += (v0 + v1) + (v2 + v3);
        }
        for (; k < cc; ++k) {
            unsigned int p = row[k >> 1];
            unsigned int s = (k & 1) ? (p >> 16) : (p & 0xFFFFu);
            acc += bf2f(m[(size_t)s * D + lane]);
        }
        if (c > CAP) {                            // rare: scan tiny ovf list (uniform)
            int oc = min(*ovf_cnt, OVF_CAP);
            for (int i = 0; i < oc; ++i) {
                unsigned int e = ovf[i];
                if ((int)(e >> 16) == node)
                    acc += bf2f(m[(size_t)(e & 0xFFFFu) * D + lane]);
            }
        }
        out[(size_t)node * D + lane] = acc;       // fully coalesced 256B/wave
    }
}

// ---------- Fallback: atomic scatter (unified m) ----------
__global__ __launch_bounds__(256) void edge_scatter_kernel(
    const int* __restrict__ src, const int* __restrict__ dst,
    const unsigned short* __restrict__ m, float* __restrict__ out, int n_edges) {
    long long t = (long long)blockIdx.x * blockDim.x + threadIdx.x;
    int e = (int)(t >> 4);
    if (e >= n_edges) return;
    int c = (int)(t & 15) << 2;
    int s = src[e];
    int d = dst[e];
    const ushort4 v = *(const ushort4*)(m + (size_t)s * D + c);
    float* o = out + (size_t)d * D + c;
    atomicAdd(o + 0, bf2f(v.x));
    atomicAdd(o + 1, bf2f(v.y));
    atomicAdd(o + 2, bf2f(v.z));
    atomicAdd(o + 3, bf2f(v.w));
}

static inline size_t align_up(size_t v, size_t a) { return (v + a - 1) & ~(a - 1); }

extern "C" void kernel_launch(void* const* d_in, const int* in_sizes, int n_in,
                              void* d_out, int out_size, void* d_ws, size_t ws_size,
                              hipStream_t stream) {
    const float* x = (const float*)d_in[0];
    const int* edge_index = (const int*)d_in[1];   // int32 per harness contract
    const float* W = (const float*)d_in[2];
    const float* b = (const float*)d_in[3];
    float* out = (float*)d_out;

    const int n_nodes = in_sizes[0] / D;        // 50000
    const int n_edges = in_sizes[1] / 2;        // 800000
    const int* src = edge_index;                // row 0 (j, gather)
    const int* dst = edge_index + n_edges;      // row 1 (i, scatter)

    // Workspace layout (~13 MB total incl. probe shadow)
    size_t off = 0;
    unsigned short* m = (unsigned short*)((char*)d_ws + off);
    off = align_up(off + (size_t)n_nodes * D * sizeof(unsigned short), 256);
    int* cnt = (int*)((char*)d_ws + off);
    off = align_up(off + (size_t)n_nodes * sizeof(int), 256);
    unsigned short* slots = (unsigned short*)((char*)d_ws + off);
    off = align_up(off + (size_t)n_nodes * CAP * sizeof(unsigned short), 256);
    int* ovf_cnt = (int*)((char*)d_ws + off);
    off = align_up(off + sizeof(int), 256);
    unsigned int* ovf = (unsigned int*)((char*)d_ws + off);
    off = align_up(off + (size_t)OVF_CAP * sizeof(unsigned int), 256);
    unsigned short* slots2 = (unsigned short*)((char*)d_ws + off);   // probe shadow
    off = align_up(off + (size_t)n_nodes * CAP * sizeof(unsigned short), 256);
    const size_t needed = off;

    // Node MLP (+ fused cnt/ovf zeroing): 512 blocks -> 8 waves/CU
    node_mlp_kernel<<<512, 256, 0, stream>>>(x, W, b, m, cnt, ovf_cnt, n_nodes);

    if (ws_size >= needed && n_nodes <= 65536) {
        const int blocks_per_shard = 320;           // 2560 blocks (r16 best)
        append_kernel<<<blocks_per_shard * NSHARD, 256, 0, stream>>>(
            src, dst, cnt, slots, slots2, ovf_cnt, ovf, n_edges, blocks_per_shard);
        const int ngroups = (n_nodes + 31) / 32;    // 8 blocks per 32-node group
        gather_kernel<<<ngroups * 8, 256, 0, stream>>>(
            slots, cnt, m, ovf_cnt, ovf, out, n_nodes);
    } else {
        hipMemsetAsync(d_out, 0, (size_t)out_size * sizeof(float), stream);
        long long total_threads = (long long)n_edges * 16;
        int scat_blocks = (int)((total_threads + 255) / 256);
        edge_scatter_kernel<<<scat_blocks, 256, 0, stream>>>(src, dst, m, out, n_edges);
    }
}

// Round 3
// 156.056 us; speedup vs baseline: 4.4279x; 4.4279x over previous
//
#include <hip/hip_runtime.h>
#include <hip/hip_bf16.h>

#define D 64
#define CAP 32      // slots per node = one 64B line (row == line)
#define OVF_CAP 16384
#define NSHARD 8    // dst shards, bound to XCDs via blockIdx&7 heuristic

// r19 probe decomposition (16x/8x/8x idempotent reps):
//   M(node_mlp)=25.2us  A+X(append+gather)=22.2us  V(harness fills/reset)=109.7us
// => only ~47us of the 157us is controllable; MLP is the biggest kernel cost.
// r20: MLP was latency-bound (VALUBusy 30%, Occ 21%: ONE 64-deep serial FMA
// chain/wave @ 2 waves/SIMD). Fix: 2 rows/wave (2 chains) + 1024-block grid
// (4 waves/SIMD). Per-row chain order unchanged -> bit-identical numerics.
// r21: resubmit — r20 bench was an infra failure (container acquire), not
// a kernel failure; no code path changed.

__device__ __forceinline__ float bf2f(unsigned short u) {
    return __uint_as_float((unsigned int)u << 16);
}
__device__ __forceinline__ unsigned short f2bf(float f) {
    unsigned int u = __float_as_uint(f);
    unsigned int r = (u + 0x7fffu + ((u >> 16) & 1u)) >> 16;   // RNE
    return (unsigned short)r;
}

// ---------- Kernel 1: m[n][:] = bf16(relu(x @ W + b)); zero cnt/ovf ----------
__global__ __launch_bounds__(256) void node_mlp_kernel(
    const float* __restrict__ x, const float* __restrict__ W,
    const float* __restrict__ b, unsigned short* __restrict__ m,
    int* __restrict__ cnt, int* __restrict__ ovf_cnt, int n_nodes) {
    for (int i = blockIdx.x * blockDim.x + threadIdx.x; i < n_nodes;
         i += gridDim.x * blockDim.x) cnt[i] = 0;
    if (blockIdx.x == 0 && threadIdx.x == 0) *ovf_cnt = 0;

    const int lane = threadIdx.x & 63;
    float w[D];
    #pragma unroll
    for (int k = 0; k < D; ++k) w[k] = W[k * D + lane];
    const float bias = b[lane];

    const int wave = (blockIdx.x * blockDim.x + threadIdx.x) >> 6;
    const int nwaves = (gridDim.x * blockDim.x) >> 6;

    // Two rows per iteration: two independent FMA chains interleave on the
    // SIMD (dependent-FMA latency ~4cyc; one chain alone caps issue at 25%).
    for (int row = wave * 2; row < n_nodes; row += nwaves * 2) {
        const int row1 = (row + 1 < n_nodes) ? row + 1 : row;
        const float4* xr0 = (const float4*)(x + (size_t)row  * D);
        const float4* xr1 = (const float4*)(x + (size_t)row1 * D);
        float acc0 = bias;
        float acc1 = bias;
        #pragma unroll
        for (int kk = 0; kk < D / 4; ++kk) {
            float4 a = xr0[kk];   // wave-uniform address -> broadcast, 1 request
            float4 c = xr1[kk];
            acc0 = fmaf(a.x, w[4 * kk + 0], acc0);
            acc1 = fmaf(c.x, w[4 * kk + 0], acc1);
            acc0 = fmaf(a.y, w[4 * kk + 1], acc0);
            acc1 = fmaf(c.y, w[4 * kk + 1], acc1);
            acc0 = fmaf(a.z, w[4 * kk + 2], acc0);
            acc1 = fmaf(c.z, w[4 * kk + 2], acc1);
            acc0 = fmaf(a.w, w[4 * kk + 3], acc0);
            acc1 = fmaf(c.w, w[4 * kk + 3], acc1);
        }
        m[(size_t)row * D + lane] = f2bf(fmaxf(acc0, 0.0f));
        if (row1 > row)
            m[(size_t)row1 * D + lane] = f2bf(fmaxf(acc1, 0.0f));
    }
}

// ---------- Kernel 2: XCD-sharded append (r12 form) ----------
// Block group k (blockIdx&7==k) handles only dst with (d&7)==k; co-resident
// blocks share an XCD under round-robin dispatch, so each slot line is
// written by one L2 and merges into a single writeback (round 12 win).
// NOTE r18: do NOT fuse phases into one kernel — the required agent-scope
// fences invalidate per-XCD L2s and cost 3x (FETCH 50->287 MB).
__global__ __launch_bounds__(256) void append_kernel(
    const int* __restrict__ src, const int* __restrict__ dst,
    int* __restrict__ cnt, unsigned short* __restrict__ slots,
    int* __restrict__ ovf_cnt, unsigned int* __restrict__ ovf,
    int n_edges, int blocks_per_shard) {
    const int shard = blockIdx.x & (NSHARD - 1);
    const int p = blockIdx.x >> 3;          // rank within shard group
    const int chunk = (n_edges + blocks_per_shard - 1) / blocks_per_shard;
    const int beg = p * chunk;
    const int end = min(beg + chunk, n_edges);

    for (int e = beg + (int)threadIdx.x; e < end; e += 256) {
        int d = dst[e];                      // coalesced; L3-served (8x redundant)
        if ((d & (NSHARD - 1)) != shard) continue;
        int s = src[e];
        int pos = atomicAdd(&cnt[d], 1);     // memory-side atomic
        if (pos < CAP) {
            slots[(size_t)d * CAP + pos] = (unsigned short)s;
        } else {                             // ~4 nodes expected (P(deg>32)~8e-5)
            int op = atomicAdd(ovf_cnt, 1);
            if (op < OVF_CAP)
                ovf[op] = ((unsigned int)d << 16) | (unsigned int)s;
        }
    }
}

// ---------- Kernel 3: gather — one wave/node, fully scalar addressing (r15 win) ----------
__global__ __launch_bounds__(256) void gather_kernel(
    const unsigned short* __restrict__ slots, const int* __restrict__ cnt,
    const unsigned short* __restrict__ m,
    const int* __restrict__ ovf_cnt, const unsigned int* __restrict__ ovf,
    float* __restrict__ out, int n_nodes) {
    const int grp = blockIdx.x >> 3;          // 8-block group covers 32 nodes
    const int xcd = blockIdx.x & 7;
    int node = grp * 32 + ((threadIdx.x >> 6) << 3) + xcd;  // node&7 == blockIdx&7
    if (node >= n_nodes) return;              // wave-uniform branch
    node = __builtin_amdgcn_readfirstlane(node);

    const int lane = threadIdx.x & 63;

    const int c = cnt[node];                  // scalar load
    const int cc = min(c, CAP);
    const unsigned int* __restrict__ row =
        (const unsigned int*)(slots + (size_t)node * CAP);  // scalar base

    float acc = 0.0f;
    int k = 0;
    for (; k + 16 <= cc; k += 16) {
        unsigned int p[8];
        #pragma unroll
        for (int i = 0; i < 8; ++i) p[i] = row[(k >> 1) + i];  // s_load x8
        float v[16];
        #pragma unroll
        for (int i = 0; i < 8; ++i) {         // 16 saddr loads in flight
            const unsigned short* ba = m + (size_t)(p[i] & 0xFFFFu) * D; // SGPR base
            const unsigned short* bb = m + (size_t)(p[i] >> 16) * D;     // SGPR base
            v[2 * i + 0] = bf2f(ba[lane]);    // global_load_ushort v, vlane2, s[..]
            v[2 * i + 1] = bf2f(bb[lane]);
        }
        float t0 = ((v[0] + v[1]) + (v[2] + v[3])) + ((v[4] + v[5]) + (v[6] + v[7]));
        float t1 = ((v[8] + v[9]) + (v[10] + v[11])) + ((v[12] + v[13]) + (v[14] + v[15]));
        acc += t0 + t1;
    }
    for (; k + 4 <= cc; k += 4) {
        unsigned int p0 = row[(k >> 1) + 0];
        unsigned int p1 = row[(k >> 1) + 1];
        const unsigned short* b0 = m + (size_t)(p0 & 0xFFFFu) * D;
        const unsigned short* b1 = m + (size_t)(p0 >> 16) * D;
        const unsigned short* b2 = m + (size_t)(p1 & 0xFFFFu) * D;
        const unsigned short* b3 = m + (size_t)(p1 >> 16) * D;
        float v0 = bf2f(b0[lane]);
        float v1 = bf2f(b1[lane]);
        float v2 = bf2f(b2[lane]);
        float v3 = bf2f(b3[lane]);
        acc += (v0 + v1) + (v2 + v3);
    }
    for (; k < cc; ++k) {
        unsigned int p = row[k >> 1];
        unsigned int s = (k & 1) ? (p >> 16) : (p & 0xFFFFu);
        acc += bf2f(m[(size_t)s * D + lane]);
    }
    if (c > CAP) {                            // rare: scan tiny ovf list (uniform)
        int oc = min(*ovf_cnt, OVF_CAP);
        for (int i = 0; i < oc; ++i) {
            unsigned int e = ovf[i];
            if ((int)(e >> 16) == node)
                acc += bf2f(m[(size_t)(e & 0xFFFFu) * D + lane]);
        }
    }
    out[(size_t)node * D + lane] = acc;       // fully coalesced 256B/wave
}

// ---------- Fallback: atomic scatter (unified m) ----------
__global__ __launch_bounds__(256) void edge_scatter_kernel(
    const int* __restrict__ src, const int* __restrict__ dst,
    const unsigned short* __restrict__ m, float* __restrict__ out, int n_edges) {
    long long t = (long long)blockIdx.x * blockDim.x + threadIdx.x;
    int e = (int)(t >> 4);
    if (e >= n_edges) return;
    int c = (int)(t & 15) << 2;
    int s = src[e];
    int d = dst[e];
    const ushort4 v = *(const ushort4*)(m + (size_t)s * D + c);
    float* o = out + (size_t)d * D + c;
    atomicAdd(o + 0, bf2f(v.x));
    atomicAdd(o + 1, bf2f(v.y));
    atomicAdd(o + 2, bf2f(v.z));
    atomicAdd(o + 3, bf2f(v.w));
}

static inline size_t align_up(size_t v, size_t a) { return (v + a - 1) & ~(a - 1); }

extern "C" void kernel_launch(void* const* d_in, const int* in_sizes, int n_in,
                              void* d_out, int out_size, void* d_ws, size_t ws_size,
                              hipStream_t stream) {
    const float* x = (const float*)d_in[0];
    const int* edge_index = (const int*)d_in[1];   // int32 per harness contract
    const float* W = (const float*)d_in[2];
    const float* b = (const float*)d_in[3];
    float* out = (float*)d_out;

    const int n_nodes = in_sizes[0] / D;        // 50000
    const int n_edges = in_sizes[1] / 2;        // 800000
    const int* src = edge_index;                // row 0 (j, gather)
    const int* dst = edge_index + n_edges;      // row 1 (i, scatter)

    // Workspace layout (~10 MB total)
    size_t off = 0;
    unsigned short* m = (unsigned short*)((char*)d_ws + off);
    off = align_up(off + (size_t)n_nodes * D * sizeof(unsigned short), 256);
    int* cnt = (int*)((char*)d_ws + off);
    off = align_up(off + (size_t)n_nodes * sizeof(int), 256);
    unsigned short* slots = (unsigned short*)((char*)d_ws + off);
    off = align_up(off + (size_t)n_nodes * CAP * sizeof(unsigned short), 256);
    int* ovf_cnt = (int*)((char*)d_ws + off);
    off = align_up(off + sizeof(int), 256);
    unsigned int* ovf = (unsigned int*)((char*)d_ws + off);
    off = align_up(off + (size_t)OVF_CAP * sizeof(unsigned int), 256);
    const size_t needed = off;

    // Node MLP (+ fused cnt/ovf zeroing): 1024 blocks -> 4 waves/SIMD resident
    node_mlp_kernel<<<1024, 256, 0, stream>>>(x, W, b, m, cnt, ovf_cnt, n_nodes);

    if (ws_size >= needed && n_nodes <= 65536) {
        const int blocks_per_shard = 320;           // 2560 blocks (r16 best)
        append_kernel<<<blocks_per_shard * NSHARD, 256, 0, stream>>>(
            src, dst, cnt, slots, ovf_cnt, ovf, n_edges, blocks_per_shard);
        const int ngroups = (n_nodes + 31) / 32;    // 8 blocks per 32-node group
        gather_kernel<<<ngroups * 8, 256, 0, stream>>>(
            slots, cnt, m, ovf_cnt, ovf, out, n_nodes);
    } else {
        hipMemsetAsync(d_out, 0, (size_t)out_size * sizeof(float), stream);
        long long total_threads = (long long)n_edges * 16;
        int scat_blocks = (int)((total_threads + 255) / 256);
        edge_scatter_kernel<<<scat_blocks, 256, 0, stream>>>(src, dst, m, out, n_edges);
    }
}